// Round 1
// baseline (73648.541 us; speedup 1.0000x reference)
//
#include <hip/hip_runtime.h>

// MDN-RNN persistent kernel for MI355X (gfx950).
// B=128, T=1000, D_IN=35, H=512, OUT=480.
// Decomposition: 8 batch-groups (16 batches each) x 32 h-slice WGs (16 h cols each)
// = 256 WGs, one per CU (forced by ~114 KB LDS). Wr/Wk/Wd slices live in LDS (bf16,
// XOR-swizzled). c stays in registers. h exchanged per step through a double-buffered
// global buffer + per-group atomic epoch barrier. Output GEMM fused (waves 4-7).

#define NGRP   8
#define NSLICE 32
#define GB     16     // batches per group
#define HH     512
#define TT     1000
#define DIN    35
#define OUTC   480
#define ODC    15     // out cols per WG (480/32)

typedef __bf16 bf16x8 __attribute__((ext_vector_type(8)));
typedef float  f32x4  __attribute__((ext_vector_type(4)));
typedef unsigned short u16;

__device__ __forceinline__ u16 f2bf(float x) {
    unsigned int u = __float_as_uint(x);
    u += 0x7FFFu + ((u >> 16) & 1u);          // round-to-nearest-even
    return (u16)(u >> 16);
}
__device__ __forceinline__ float sigf(float x) {
    return 1.0f / (1.0f + __expf(-x));
}
__device__ __forceinline__ float tanh_fast(float x) {
    float ax = fabsf(x);
    float e = __expf(-2.0f * ax);
    float t = (1.0f - e) / (1.0f + e);
    return copysignf(t, x);
}

__global__ void __launch_bounds__(512, 1)
mdn_kernel(const float* __restrict__ inp, const float* __restrict__ Wk,
           const float* __restrict__ Wr,  const float* __restrict__ bg,
           const float* __restrict__ Wd,  const float* __restrict__ bd,
           float* __restrict__ out, u16* __restrict__ hglob, int* __restrict__ bar)
{
    // LDS tiles, all [row][k] with element-XOR swizzle  k ^= (row&7)<<3  (16B-block swizzle)
    __shared__ __attribute__((aligned(16))) u16  wr_s[64 * HH];   // 64 gate cols x 512  (64 KB)
    __shared__ __attribute__((aligned(16))) u16  wk_s[64 * 64];   // 64 gate cols x 64 (k>=35 zero)
    __shared__ __attribute__((aligned(16))) u16  wd_s[16 * HH];   // 16 out cols (col15 zero) x 512
    __shared__ __attribute__((aligned(16))) u16  h_s [GB * HH];   // staged h_{t-1}
    __shared__ __attribute__((aligned(16))) u16  in_s[GB * 64];   // x_t, zero-padded d>=35
    __shared__ __attribute__((aligned(16))) float gbuf[4 * 16 * 16]; // gates [q][col][b]
    __shared__ __attribute__((aligned(16))) float pbuf[4 * 16 * 16]; // out partials [kw][col][b]

    const int tid  = threadIdx.x;
    const int lane = tid & 63;
    const int wave = tid >> 6;
    const int g    = blockIdx.x & 7;    // batch group (XCD-affine under round-robin)
    const int s    = blockIdx.x >> 3;   // h-slice 0..31

    // ---------------- one-time weight staging ----------------
    {
        int n = tid & 63;                       // local gate col 0..63
        int q = n >> 4, jj = n & 15;
        int col = q * HH + s * 16 + jj;         // global gate col
        for (int k = tid >> 6; k < HH; k += 8)
            wr_s[n * HH + (k ^ ((n & 7) << 3))] = f2bf(Wr[(size_t)k * 2048 + col]);
        for (int k = tid >> 6; k < 64; k += 8)
            wk_s[n * 64 + (k ^ ((n & 7) << 3))] = f2bf(k < DIN ? Wk[(size_t)k * 2048 + col] : 0.0f);
    }
    {
        int n = tid & 15;
        for (int k = tid >> 4; k < HH; k += 32)
            wd_s[n * HH + (k ^ ((n & 7) << 3))] =
                f2bf(n < ODC ? Wd[(size_t)k * OUTC + s * ODC + n] : 0.0f);
    }
    for (int i = tid; i < GB * 64; i += 512) in_s[i] = 0;  // pad slots stay 0 forever

    // ---------------- per-thread persistent state ----------------
    float c_reg = 0.0f;
    float bi = 0.f, bff = 0.f, bgg = 0.f, boo = 0.f, bdv = 0.f;
    int br = 0, jj = 0, oo = 0;
    if (tid < 256) {
        br = tid >> 4; jj = tid & 15;
        int scol = s * 16 + jj;
        bi  = bg[0 * HH + scol];
        bff = bg[1 * HH + scol];
        bgg = bg[2 * HH + scol];
        boo = bg[3 * HH + scol];
    } else {
        br = (tid - 256) >> 4; oo = (tid - 256) & 15;
        if (oo < ODC) bdv = bd[s * ODC + oo];
    }

    __syncthreads();

    const int m16 = lane & 15;   // A-row / B-col within fragment
    const int kq  = lane >> 4;   // k-subgroup 0..3 (8 elems each)

    for (int t = 0; t <= TT; ++t) {
        // ---- stage h_{t-1} from global double buffer ((t+1)&1) ----
        {
            const u16* hsrc = hglob + ((size_t)(g * 2 + ((t + 1) & 1))) * GB * HH;
            int b = tid >> 5, kc = tid & 31;
            #pragma unroll
            for (int i = 0; i < 2; ++i) {
                int k = kc * 8 + i * 256;
                uint4 v = *(const uint4*)(hsrc + b * HH + k);
                *(uint4*)(&h_s[b * HH + (k ^ ((b & 7) << 3))]) = v;
            }
        }
        // ---- stage x_t ----
        if (t < TT && tid < 256) {
            int b = tid >> 4, d0 = tid & 15;
            const float* ip = inp + ((size_t)(g * GB + b) * TT + t) * DIN;
            #pragma unroll
            for (int i = 0; i < 3; ++i) {
                int d = d0 + 16 * i;
                if (d < DIN) in_s[b * 64 + (d ^ ((b & 7) << 3))] = f2bf(ip[d]);
            }
        }
        __syncthreads();

        // ---- MFMA phase ----
        if (wave < 4) {
            if (t < TT) {                       // gates for gate-type q = wave
                int q = wave;
                int n = q * 16 + m16;
                f32x4 acc = {0.f, 0.f, 0.f, 0.f};
                #pragma unroll
                for (int ks = 0; ks < 2; ++ks) { // xz contribution (K padded 35->64)
                    int k0 = 32 * ks + 8 * kq;
                    bf16x8 a = *(const bf16x8*)(&in_s[m16 * 64 + (k0 ^ ((m16 & 7) << 3))]);
                    bf16x8 b = *(const bf16x8*)(&wk_s[n  * 64 + (k0 ^ ((n  & 7) << 3))]);
                    acc = __builtin_amdgcn_mfma_f32_16x16x32_bf16(a, b, acc, 0, 0, 0);
                }
                #pragma unroll 4
                for (int ks = 0; ks < 16; ++ks) { // h @ Wr
                    int k0 = 32 * ks + 8 * kq;
                    bf16x8 a = *(const bf16x8*)(&h_s [m16 * HH + (k0 ^ ((m16 & 7) << 3))]);
                    bf16x8 b = *(const bf16x8*)(&wr_s[n   * HH + (k0 ^ ((n   & 7) << 3))]);
                    acc = __builtin_amdgcn_mfma_f32_16x16x32_bf16(a, b, acc, 0, 0, 0);
                }
                *(f32x4*)(&gbuf[q * 256 + m16 * 16 + kq * 4]) = acc;  // [q][col][b] col-major
            }
        } else {
            if (t > 0) {                        // out row t-1, k-split across waves 4..7
                int w4 = wave - 4;
                f32x4 acc = {0.f, 0.f, 0.f, 0.f};
                #pragma unroll
                for (int kk = 0; kk < 4; ++kk) {
                    int k0 = w4 * 128 + 32 * kk + 8 * kq;
                    bf16x8 a = *(const bf16x8*)(&h_s [m16 * HH + (k0 ^ ((m16 & 7) << 3))]);
                    bf16x8 b = *(const bf16x8*)(&wd_s[m16 * HH + (k0 ^ ((m16 & 7) << 3))]);
                    acc = __builtin_amdgcn_mfma_f32_16x16x32_bf16(a, b, acc, 0, 0, 0);
                }
                *(f32x4*)(&pbuf[w4 * 256 + m16 * 16 + kq * 4]) = acc;
            }
        }
        __syncthreads();

        // ---- scalar phase ----
        if (tid < 256) {
            if (t < TT) {                       // LSTM cell update for (batch br, h col jj)
                float iv = gbuf[0 * 256 + jj * 16 + br] + bi;
                float fv = gbuf[1 * 256 + jj * 16 + br] + bff;
                float gv = gbuf[2 * 256 + jj * 16 + br] + bgg;
                float ov = gbuf[3 * 256 + jj * 16 + br] + boo;
                c_reg = sigf(fv) * c_reg + sigf(iv) * tanh_fast(gv);
                float h = sigf(ov) * tanh_fast(c_reg);
                hglob[((size_t)(g * 2 + (t & 1))) * GB * HH + br * HH + s * 16 + jj] = f2bf(h);
            }
        } else {
            if (t > 0) {                        // reduce out partials + store f32
                float v = pbuf[0 * 256 + oo * 16 + br] + pbuf[1 * 256 + oo * 16 + br]
                        + pbuf[2 * 256 + oo * 16 + br] + pbuf[3 * 256 + oo * 16 + br] + bdv;
                if (oo < ODC)
                    out[((size_t)(g * GB + br) * TT + (t - 1)) * OUTC + s * ODC + oo] = v;
            }
        }

        // ---- per-group device barrier (epoch counter, release/acquire) ----
        if (t < TT) {
            __threadfence();                    // publish h stores device-wide
            __syncthreads();
            if (tid == 0) {
                __hip_atomic_fetch_add(&bar[g * 64], 1, __ATOMIC_RELEASE, __HIP_MEMORY_SCOPE_AGENT);
                int target = NSLICE * (t + 1);
                int spins = 0;
                while (__hip_atomic_load(&bar[g * 64], __ATOMIC_ACQUIRE,
                                         __HIP_MEMORY_SCOPE_AGENT) < target) {
                    __builtin_amdgcn_s_sleep(1);
                    if (++spins > (1 << 22)) break;   // bounded bail-out: no hangs
                }
            }
            __threadfence();                    // acquire side: invalidate stale caches
            __syncthreads();
        }
    }
}

extern "C" void kernel_launch(void* const* d_in, const int* in_sizes, int n_in,
                              void* d_out, int out_size, void* d_ws, size_t ws_size,
                              hipStream_t stream) {
    const float* inp = (const float*)d_in[0];
    const float* Wk  = (const float*)d_in[1];
    const float* Wr  = (const float*)d_in[2];
    const float* bg  = (const float*)d_in[3];
    const float* Wd  = (const float*)d_in[4];
    const float* bd  = (const float*)d_in[5];
    float* out = (float*)d_out;

    // ws layout: [0,4096): per-group barrier counters (padded 256B apart)
    //            [4096, 4096+262144): h double buffers, 8 groups x 2 x 16 x 512 bf16
    char* ws = (char*)d_ws;
    int* bar = (int*)ws;
    u16* hglob = (u16*)(ws + 4096);
    size_t zbytes = 4096 + (size_t)NGRP * 2 * GB * HH * sizeof(u16);
    hipMemsetAsync(d_ws, 0, zbytes, stream);   // zero h0 + barrier epochs every launch

    hipLaunchKernelGGL(mdn_kernel, dim3(NGRP * NSLICE), dim3(512), 0, stream,
                       inp, Wk, Wr, bg, Wd, bd, out, hglob, bar);
}

// Round 3
// 67336.267 us; speedup vs baseline: 1.0937x; 1.0937x over previous
//
#include <hip/hip_runtime.h>

// MDN-RNN persistent kernel for MI355X (gfx950).  R3 = R2 + preamble race fix.
// B=128, T=1000, D_IN=35, H=512, OUT=480.
// 8 batch-groups (16 batches) x 32 h-slice WGs (16 h cols / 64 gate cols) = 256 WGs.
// Wr/Wk/Wd slices in LDS (bf16, XOR-swizzled). c in registers. h exchanged per step
// via double-buffered global buffer; per-group barrier = 32 epoch flags (64B apart,
// plain release stores) polled by wave 0's 32 lanes in one strided load + ballot.
// R3 fix: __syncthreads() between in_s zero-init and x_0 staging (wave 4-7 zero
// stores could land after wave 0-3 x_0 stores, corrupting x_0 -> absmax 0.148).

#define NGRP   8
#define NSLICE 32
#define GB     16
#define HH     512
#define TT     1000
#define DIN    35
#define OUTC   480
#define ODC    15

typedef __bf16 bf16x8 __attribute__((ext_vector_type(8)));
typedef float  f32x4  __attribute__((ext_vector_type(4)));
typedef unsigned short u16;

__device__ __forceinline__ u16 f2bf(float x) {
    unsigned int u = __float_as_uint(x);
    u += 0x7FFFu + ((u >> 16) & 1u);
    return (u16)(u >> 16);
}
__device__ __forceinline__ float sigf(float x) { return 1.0f / (1.0f + __expf(-x)); }
__device__ __forceinline__ float tanh_fast(float x) {
    float ax = fabsf(x);
    float e = __expf(-2.0f * ax);
    return copysignf((1.0f - e) / (1.0f + e), x);
}

__global__ void __launch_bounds__(512, 1)
mdn_kernel(const float* __restrict__ inp, const float* __restrict__ Wk,
           const float* __restrict__ Wr,  const float* __restrict__ bg,
           const float* __restrict__ Wd,  const float* __restrict__ bd,
           float* __restrict__ out, u16* __restrict__ hglob, int* __restrict__ bar)
{
    __shared__ __attribute__((aligned(16))) u16  wr_s[64 * HH];
    __shared__ __attribute__((aligned(16))) u16  wk_s[64 * 64];
    __shared__ __attribute__((aligned(16))) u16  wd_s[16 * HH];
    __shared__ __attribute__((aligned(16))) u16  h_s [GB * HH];
    __shared__ __attribute__((aligned(16))) u16  in_s[GB * 64];
    __shared__ __attribute__((aligned(16))) float gbuf[4 * 16 * 16]; // [q][batch][col]
    __shared__ __attribute__((aligned(16))) float pbuf[4 * 16 * 16]; // [kw][batch][col]

    const int tid  = threadIdx.x;
    const int lane = tid & 63;
    const int wave = tid >> 6;
    const int g    = blockIdx.x & 7;    // batch group (XCD-affine under round-robin)
    const int s    = blockIdx.x >> 3;   // h-slice 0..31

    // ---------------- one-time weight staging ----------------
    {
        int n = tid & 63;
        int q = n >> 4, jj = n & 15;
        int col = q * HH + s * 16 + jj;
        for (int k = tid >> 6; k < HH; k += 8)
            wr_s[n * HH + (k ^ ((n & 7) << 3))] = f2bf(Wr[(size_t)k * 2048 + col]);
        for (int k = tid >> 6; k < 64; k += 8)
            wk_s[n * 64 + (k ^ ((n & 7) << 3))] = f2bf(k < DIN ? Wk[(size_t)k * 2048 + col] : 0.0f);
    }
    {
        int n = tid & 15;
        for (int k = tid >> 4; k < HH; k += 32)
            wd_s[n * HH + (k ^ ((n & 7) << 3))] =
                f2bf(n < ODC ? Wd[(size_t)k * OUTC + s * ODC + n] : 0.0f);
    }
    for (int i = tid; i < GB * 64; i += 512) in_s[i] = 0;
    for (int i = tid; i < GB * HH / 8; i += 512) ((uint4*)h_s)[i] = uint4{0,0,0,0}; // h_{-1}=0

    __syncthreads();   // R3 FIX: order zero-init before x_0 staging across waves

    // ---------------- per-thread persistent state ----------------
    float c_reg = 0.0f;
    float bi = 0.f, bff = 0.f, bgg = 0.f, boo = 0.f, bdv = 0.f;
    int br = 0, jj = 0, oo = 0;
    if (tid < 256) {
        br = tid >> 4; jj = tid & 15;
        int scol = s * 16 + jj;
        bi  = bg[0 * HH + scol];
        bff = bg[1 * HH + scol];
        bgg = bg[2 * HH + scol];
        boo = bg[3 * HH + scol];
    } else {
        br = (tid - 256) >> 4; oo = (tid - 256) & 15;
        if (oo < ODC) bdv = bd[s * ODC + oo];
    }
    // stage x_0
    if (tid < 256) {
        int b = tid >> 4, d0 = tid & 15;
        const float* ip = inp + ((size_t)(g * GB + b) * TT + 0) * DIN;
        #pragma unroll
        for (int i = 0; i < 3; ++i) {
            int d = d0 + 16 * i;
            if (d < DIN) in_s[b * 64 + (d ^ ((b & 7) << 3))] = f2bf(ip[d]);
        }
    }
    __syncthreads();

    const int m16 = lane & 15;
    const int kq  = lane >> 4;

    for (int t = 0; t <= TT; ++t) {
        // top invariant: h_s = h_{t-1}, in_s = x_t
        // ---- MFMA phase ----
        if (wave < 4) {
            if (t < TT) {
                int q = wave;
                int n = q * 16 + m16;
                f32x4 acc0 = {0.f,0.f,0.f,0.f}, acc1 = {0.f,0.f,0.f,0.f};
                {   // xz contribution (K padded 35->64)
                    int k0 = 8 * kq;
                    bf16x8 a = *(const bf16x8*)(&in_s[m16 * 64 + (k0 ^ ((m16 & 7) << 3))]);
                    bf16x8 b = *(const bf16x8*)(&wk_s[n  * 64 + (k0 ^ ((n  & 7) << 3))]);
                    acc0 = __builtin_amdgcn_mfma_f32_16x16x32_bf16(a, b, acc0, 0, 0, 0);
                    int k1 = 32 + 8 * kq;
                    bf16x8 a2 = *(const bf16x8*)(&in_s[m16 * 64 + (k1 ^ ((m16 & 7) << 3))]);
                    bf16x8 b2 = *(const bf16x8*)(&wk_s[n  * 64 + (k1 ^ ((n  & 7) << 3))]);
                    acc1 = __builtin_amdgcn_mfma_f32_16x16x32_bf16(a2, b2, acc1, 0, 0, 0);
                }
                #pragma unroll
                for (int ks = 0; ks < 16; ks += 2) {   // h @ Wr, 2-way ILP
                    int k0 = 32 * ks + 8 * kq;
                    bf16x8 a = *(const bf16x8*)(&h_s [m16 * HH + (k0 ^ ((m16 & 7) << 3))]);
                    bf16x8 b = *(const bf16x8*)(&wr_s[n   * HH + (k0 ^ ((n   & 7) << 3))]);
                    acc0 = __builtin_amdgcn_mfma_f32_16x16x32_bf16(a, b, acc0, 0, 0, 0);
                    int k1 = 32 * (ks + 1) + 8 * kq;
                    bf16x8 a2 = *(const bf16x8*)(&h_s [m16 * HH + (k1 ^ ((m16 & 7) << 3))]);
                    bf16x8 b2 = *(const bf16x8*)(&wr_s[n   * HH + (k1 ^ ((n   & 7) << 3))]);
                    acc1 = __builtin_amdgcn_mfma_f32_16x16x32_bf16(a2, b2, acc1, 0, 0, 0);
                }
                #pragma unroll
                for (int j = 0; j < 4; ++j)   // [q][batch][col] — conflict-free b32 stores
                    gbuf[q * 256 + (kq * 4 + j) * 16 + m16] = acc0[j] + acc1[j];
            }
        } else {
            if (t > 0) {    // out row t-1, k-split across waves 4..7
                int w4 = wave - 4;
                f32x4 acc0 = {0.f,0.f,0.f,0.f}, acc1 = {0.f,0.f,0.f,0.f};
                #pragma unroll
                for (int kk = 0; kk < 4; kk += 2) {
                    int k0 = w4 * 128 + 32 * kk + 8 * kq;
                    bf16x8 a = *(const bf16x8*)(&h_s [m16 * HH + (k0 ^ ((m16 & 7) << 3))]);
                    bf16x8 b = *(const bf16x8*)(&wd_s[m16 * HH + (k0 ^ ((m16 & 7) << 3))]);
                    acc0 = __builtin_amdgcn_mfma_f32_16x16x32_bf16(a, b, acc0, 0, 0, 0);
                    int k1 = w4 * 128 + 32 * (kk + 1) + 8 * kq;
                    bf16x8 a2 = *(const bf16x8*)(&h_s [m16 * HH + (k1 ^ ((m16 & 7) << 3))]);
                    bf16x8 b2 = *(const bf16x8*)(&wd_s[m16 * HH + (k1 ^ ((m16 & 7) << 3))]);
                    acc1 = __builtin_amdgcn_mfma_f32_16x16x32_bf16(a2, b2, acc1, 0, 0, 0);
                }
                #pragma unroll
                for (int j = 0; j < 4; ++j)
                    pbuf[w4 * 256 + (kq * 4 + j) * 16 + m16] = acc0[j] + acc1[j];
            }
        }
        __syncthreads();                                   // #1

        // ---- scalar phase ----
        if (tid < 256) {
            if (t < TT) {
                float iv = gbuf[0 * 256 + br * 16 + jj] + bi;
                float fv = gbuf[1 * 256 + br * 16 + jj] + bff;
                float gv = gbuf[2 * 256 + br * 16 + jj] + bgg;
                float ov = gbuf[3 * 256 + br * 16 + jj] + boo;
                c_reg = sigf(fv) * c_reg + sigf(iv) * tanh_fast(gv);
                float h = sigf(ov) * tanh_fast(c_reg);
                hglob[((size_t)(g * 2 + (t & 1))) * GB * HH + br * HH + s * 16 + jj] = f2bf(h);
            }
        } else {
            if (t > 0) {
                float v = pbuf[0 * 256 + br * 16 + oo] + pbuf[1 * 256 + br * 16 + oo]
                        + pbuf[2 * 256 + br * 16 + oo] + pbuf[3 * 256 + br * 16 + oo] + bdv;
                if (oo < ODC)
                    out[((size_t)(g * GB + br) * TT + (t - 1)) * OUTC + s * ODC + oo] = v;
            }
        }

        if (t < TT) {
            __threadfence();                               // publish h stores
            __syncthreads();                               // #2
            if (tid == 0)                                  // publish epoch flag (no RMW)
                __hip_atomic_store(&bar[(g * NSLICE + s) * 16], t + 1,
                                   __ATOMIC_RELEASE, __HIP_MEMORY_SCOPE_AGENT);
            // stage x_{t+1} while the barrier settles (pad slots untouched: no race)
            if (t + 1 < TT && tid < 256) {
                int b = tid >> 4, d0 = tid & 15;
                const float* ip = inp + ((size_t)(g * GB + b) * TT + (t + 1)) * DIN;
                #pragma unroll
                for (int i = 0; i < 3; ++i) {
                    int d = d0 + 16 * i;
                    if (d < DIN) in_s[b * 64 + (d ^ ((b & 7) << 3))] = f2bf(ip[d]);
                }
            }
            // poll: 32 lanes of wave 0 read all 32 flags in one strided load
            if (wave == 0) {
                const int* fp = bar + (g * NSLICE + (lane & 31)) * 16;
                int target = t + 1;
                int spins = 0;
                while (true) {
                    int v = __hip_atomic_load(fp, __ATOMIC_RELAXED, __HIP_MEMORY_SCOPE_AGENT);
                    if (__all(v >= target)) break;
                    __builtin_amdgcn_s_sleep(2);
                    if (++spins > (1 << 22)) break;        // bounded bail-out: no hangs
                }
            }
            __syncthreads();                               // #3
            __threadfence();                               // acquire: invalidate stale L1
            // stage h_t from buffer (t&1)
            {
                const u16* hsrc = hglob + ((size_t)(g * 2 + (t & 1))) * GB * HH;
                int b = tid >> 5, kc = tid & 31;
                #pragma unroll
                for (int i = 0; i < 2; ++i) {
                    int k = kc * 8 + i * 256;
                    uint4 v = *(const uint4*)(hsrc + b * HH + k);
                    *(uint4*)(&h_s[b * HH + (k ^ ((b & 7) << 3))]) = v;
                }
            }
            __syncthreads();                               // #4
        }
    }
}

extern "C" void kernel_launch(void* const* d_in, const int* in_sizes, int n_in,
                              void* d_out, int out_size, void* d_ws, size_t ws_size,
                              hipStream_t stream) {
    const float* inp = (const float*)d_in[0];
    const float* Wk  = (const float*)d_in[1];
    const float* Wr  = (const float*)d_in[2];
    const float* bg  = (const float*)d_in[3];
    const float* Wd  = (const float*)d_in[4];
    const float* bd  = (const float*)d_in[5];
    float* out = (float*)d_out;

    // ws layout: [0,16384): epoch flags, (g*32+s)*16 ints (64B apart)
    //            [16384, 16384+262144): h double buffers, 8 x 2 x 16 x 512 bf16
    char* ws = (char*)d_ws;
    int* bar = (int*)ws;
    u16* hglob = (u16*)(ws + 16384);
    size_t zbytes = 16384 + (size_t)NGRP * 2 * GB * HH * sizeof(u16);
    hipMemsetAsync(d_ws, 0, zbytes, stream);

    hipLaunchKernelGGL(mdn_kernel, dim3(NGRP * NSLICE), dim3(512), 0, stream,
                       inp, Wk, Wr, bg, Wd, bd, out, hglob, bar);
}

// Round 4
// 3124.766 us; speedup vs baseline: 23.5693x; 21.5492x over previous
//
#include <hip/hip_runtime.h>

// MDN-RNN persistent kernel for MI355X (gfx950).  R4: no cache-wide ops in hot loop.
// B=128, T=1000, D_IN=35, H=512, OUT=480.
// 8 batch-groups (16 batches) x 32 h-slice WGs = 256 WGs, 1/CU (114 KB LDS).
// R1/R3 lesson: agent-scope acquire/release (threadfence, acq loads) emit
// buffer_wbl2/buffer_inv = XCD-wide L2 writeback/invalidate -> ~64 us/step storm.
// R4: ALL cross-WG traffic (h exchange, flags) uses RELAXED agent-scope atomics
// (per-access bypass to the coherence point). Ordering: explicit vmcnt(0) drain
// per wave before the pre-flag barrier (release sequence), compiler-only memory
// barrier after poll (consumer reads are bypass atomics -> always fresh).

#define NGRP   8
#define NSLICE 32
#define GB     16
#define HH     512
#define TT     1000
#define DIN    35
#define OUTC   480
#define ODC    15

typedef __bf16 bf16x8 __attribute__((ext_vector_type(8)));
typedef float  f32x4  __attribute__((ext_vector_type(4)));
typedef unsigned short u16;
typedef unsigned int   u32;
typedef unsigned long long u64;

__device__ __forceinline__ u16 f2bf(float x) {
    unsigned int u = __float_as_uint(x);
    u += 0x7FFFu + ((u >> 16) & 1u);
    return (u16)(u >> 16);
}
__device__ __forceinline__ float sigf(float x) { return 1.0f / (1.0f + __expf(-x)); }
__device__ __forceinline__ float tanh_fast(float x) {
    float ax = fabsf(x);
    float e = __expf(-2.0f * ax);
    return copysignf((1.0f - e) / (1.0f + e), x);
}

__global__ void __launch_bounds__(512, 1)
mdn_kernel(const float* __restrict__ inp, const float* __restrict__ Wk,
           const float* __restrict__ Wr,  const float* __restrict__ bg,
           const float* __restrict__ Wd,  const float* __restrict__ bd,
           float* __restrict__ out, u16* __restrict__ hglob, int* __restrict__ bar)
{
    __shared__ __attribute__((aligned(16))) u16  wr_s[64 * HH];
    __shared__ __attribute__((aligned(16))) u16  wk_s[64 * 64];
    __shared__ __attribute__((aligned(16))) u16  wd_s[16 * HH];
    __shared__ __attribute__((aligned(16))) u16  h_s [GB * HH];
    __shared__ __attribute__((aligned(16))) u16  in_s[GB * 64];
    __shared__ __attribute__((aligned(16))) float gbuf[4 * 16 * 16]; // [q][batch][col]
    __shared__ __attribute__((aligned(16))) float pbuf[4 * 16 * 16]; // [kw][batch][col]

    const int tid  = threadIdx.x;
    const int lane = tid & 63;
    const int wave = tid >> 6;
    const int g    = blockIdx.x & 7;    // batch group (XCD-affine under round-robin)
    const int s    = blockIdx.x >> 3;   // h-slice 0..31

    // ---------------- one-time weight staging ----------------
    {
        int n = tid & 63;
        int q = n >> 4, jj = n & 15;
        int col = q * HH + s * 16 + jj;
        for (int k = tid >> 6; k < HH; k += 8)
            wr_s[n * HH + (k ^ ((n & 7) << 3))] = f2bf(Wr[(size_t)k * 2048 + col]);
        for (int k = tid >> 6; k < 64; k += 8)
            wk_s[n * 64 + (k ^ ((n & 7) << 3))] = f2bf(k < DIN ? Wk[(size_t)k * 2048 + col] : 0.0f);
    }
    {
        int n = tid & 15;
        for (int k = tid >> 4; k < HH; k += 32)
            wd_s[n * HH + (k ^ ((n & 7) << 3))] =
                f2bf(n < ODC ? Wd[(size_t)k * OUTC + s * ODC + n] : 0.0f);
    }
    for (int i = tid; i < GB * 64; i += 512) in_s[i] = 0;
    for (int i = tid; i < GB * HH / 8; i += 512) ((uint4*)h_s)[i] = uint4{0,0,0,0}; // h_{-1}=0

    __syncthreads();   // order zero-init before x_0 staging across waves

    // ---------------- per-thread persistent state ----------------
    float c_reg = 0.0f;
    float bi = 0.f, bff = 0.f, bgg = 0.f, boo = 0.f, bdv = 0.f;
    int br = 0, jj = 0, oo = 0;
    if (tid < 256) {
        br = tid >> 4; jj = tid & 15;
        int scol = s * 16 + jj;
        bi  = bg[0 * HH + scol];
        bff = bg[1 * HH + scol];
        bgg = bg[2 * HH + scol];
        boo = bg[3 * HH + scol];
    } else {
        br = (tid - 256) >> 4; oo = (tid - 256) & 15;
        if (oo < ODC) bdv = bd[s * ODC + oo];
    }
    // stage x_0
    if (tid < 256) {
        int b = tid >> 4, d0 = tid & 15;
        const float* ip = inp + ((size_t)(g * GB + b) * TT + 0) * DIN;
        #pragma unroll
        for (int i = 0; i < 3; ++i) {
            int d = d0 + 16 * i;
            if (d < DIN) in_s[b * 64 + (d ^ ((b & 7) << 3))] = f2bf(ip[d]);
        }
    }
    __syncthreads();

    const int m16 = lane & 15;
    const int kq  = lane >> 4;

    for (int t = 0; t <= TT; ++t) {
        // top invariant: h_s = h_{t-1}, in_s = x_t
        // ---- MFMA phase ----
        if (wave < 4) {
            if (t < TT) {
                int q = wave;
                int n = q * 16 + m16;
                f32x4 acc0 = {0.f,0.f,0.f,0.f}, acc1 = {0.f,0.f,0.f,0.f};
                {   // xz contribution (K padded 35->64)
                    int k0 = 8 * kq;
                    bf16x8 a = *(const bf16x8*)(&in_s[m16 * 64 + (k0 ^ ((m16 & 7) << 3))]);
                    bf16x8 b = *(const bf16x8*)(&wk_s[n  * 64 + (k0 ^ ((n  & 7) << 3))]);
                    acc0 = __builtin_amdgcn_mfma_f32_16x16x32_bf16(a, b, acc0, 0, 0, 0);
                    int k1 = 32 + 8 * kq;
                    bf16x8 a2 = *(const bf16x8*)(&in_s[m16 * 64 + (k1 ^ ((m16 & 7) << 3))]);
                    bf16x8 b2 = *(const bf16x8*)(&wk_s[n  * 64 + (k1 ^ ((n  & 7) << 3))]);
                    acc1 = __builtin_amdgcn_mfma_f32_16x16x32_bf16(a2, b2, acc1, 0, 0, 0);
                }
                #pragma unroll
                for (int ks = 0; ks < 16; ks += 2) {   // h @ Wr, 2-way ILP
                    int k0 = 32 * ks + 8 * kq;
                    bf16x8 a = *(const bf16x8*)(&h_s [m16 * HH + (k0 ^ ((m16 & 7) << 3))]);
                    bf16x8 b = *(const bf16x8*)(&wr_s[n   * HH + (k0 ^ ((n   & 7) << 3))]);
                    acc0 = __builtin_amdgcn_mfma_f32_16x16x32_bf16(a, b, acc0, 0, 0, 0);
                    int k1 = 32 * (ks + 1) + 8 * kq;
                    bf16x8 a2 = *(const bf16x8*)(&h_s [m16 * HH + (k1 ^ ((m16 & 7) << 3))]);
                    bf16x8 b2 = *(const bf16x8*)(&wr_s[n   * HH + (k1 ^ ((n   & 7) << 3))]);
                    acc1 = __builtin_amdgcn_mfma_f32_16x16x32_bf16(a2, b2, acc1, 0, 0, 0);
                }
                #pragma unroll
                for (int j = 0; j < 4; ++j)   // [q][batch][col] — conflict-free b32 stores
                    gbuf[q * 256 + (kq * 4 + j) * 16 + m16] = acc0[j] + acc1[j];
            }
        } else {
            if (t > 0) {    // out row t-1, k-split across waves 4..7
                int w4 = wave - 4;
                f32x4 acc0 = {0.f,0.f,0.f,0.f}, acc1 = {0.f,0.f,0.f,0.f};
                #pragma unroll
                for (int kk = 0; kk < 4; kk += 2) {
                    int k0 = w4 * 128 + 32 * kk + 8 * kq;
                    bf16x8 a = *(const bf16x8*)(&h_s [m16 * HH + (k0 ^ ((m16 & 7) << 3))]);
                    bf16x8 b = *(const bf16x8*)(&wd_s[m16 * HH + (k0 ^ ((m16 & 7) << 3))]);
                    acc0 = __builtin_amdgcn_mfma_f32_16x16x32_bf16(a, b, acc0, 0, 0, 0);
                    int k1 = w4 * 128 + 32 * (kk + 1) + 8 * kq;
                    bf16x8 a2 = *(const bf16x8*)(&h_s [m16 * HH + (k1 ^ ((m16 & 7) << 3))]);
                    bf16x8 b2 = *(const bf16x8*)(&wd_s[m16 * HH + (k1 ^ ((m16 & 7) << 3))]);
                    acc1 = __builtin_amdgcn_mfma_f32_16x16x32_bf16(a2, b2, acc1, 0, 0, 0);
                }
                #pragma unroll
                for (int j = 0; j < 4; ++j)
                    pbuf[w4 * 256 + (kq * 4 + j) * 16 + m16] = acc0[j] + acc1[j];
            }
        }
        __syncthreads();                                   // #1

        // ---- scalar phase ----
        if (tid < 256) {
            if (t < TT) {
                float iv = gbuf[0 * 256 + br * 16 + jj] + bi;
                float fv = gbuf[1 * 256 + br * 16 + jj] + bff;
                float gv = gbuf[2 * 256 + br * 16 + jj] + bgg;
                float ov = gbuf[3 * 256 + br * 16 + jj] + boo;
                c_reg = sigf(fv) * c_reg + sigf(iv) * tanh_fast(gv);
                float h = sigf(ov) * tanh_fast(c_reg);
                // publish h via RELAXED agent atomics (cache-bypass, no wbl2/inv)
                u32 hb = (u32)f2bf(h);
                u32 other = (u32)__shfl_xor((int)hb, 1);
                if ((jj & 1) == 0) {
                    u32 packed = hb | (other << 16);       // little-endian: jj low, jj+1 high
                    u32* dst = (u32*)(hglob + ((size_t)(g * 2 + (t & 1))) * GB * HH
                                      + br * HH + s * 16 + jj);
                    __hip_atomic_store(dst, packed, __ATOMIC_RELAXED, __HIP_MEMORY_SCOPE_AGENT);
                }
            }
        } else {
            if (t > 0) {
                float v = pbuf[0 * 256 + br * 16 + oo] + pbuf[1 * 256 + br * 16 + oo]
                        + pbuf[2 * 256 + br * 16 + oo] + pbuf[3 * 256 + br * 16 + oo] + bdv;
                if (oo < ODC)
                    out[((size_t)(g * GB + br) * TT + (t - 1)) * OUTC + s * ODC + oo] = v;
            }
        }

        if (t < TT) {
            // release sequence: every wave drains its bypass-stores to the
            // coherence point, then block-barrier, then one flag store.
            asm volatile("s_waitcnt vmcnt(0)" ::: "memory");
            __syncthreads();                               // #2
            if (tid == 0)
                __hip_atomic_store(&bar[(g * NSLICE + s) * 16], t + 1,
                                   __ATOMIC_RELAXED, __HIP_MEMORY_SCOPE_AGENT);
            // stage x_{t+1} while the barrier settles (pad slots untouched: no race)
            if (t + 1 < TT && tid < 256) {
                int b = tid >> 4, d0 = tid & 15;
                const float* ip = inp + ((size_t)(g * GB + b) * TT + (t + 1)) * DIN;
                #pragma unroll
                for (int i = 0; i < 3; ++i) {
                    int d = d0 + 16 * i;
                    if (d < DIN) in_s[b * 64 + (d ^ ((b & 7) << 3))] = f2bf(ip[d]);
                }
            }
            // poll: 32 lanes of wave 0 read all 32 flags (relaxed, bypass — no inv)
            if (wave == 0) {
                const int* fp = bar + (g * NSLICE + (lane & 31)) * 16;
                int target = t + 1;
                int spins = 0;
                while (true) {
                    int v = __hip_atomic_load(fp, __ATOMIC_RELAXED, __HIP_MEMORY_SCOPE_AGENT);
                    if (__all(v >= target)) break;
                    __builtin_amdgcn_s_sleep(1);
                    if (++spins > (1 << 22)) break;        // bounded bail-out: no hangs
                }
            }
            __syncthreads();                               // #3
            asm volatile("" ::: "memory");                 // compiler-only: no hoisting
            // stage h_t from buffer (t&1) via RELAXED agent atomic loads (always fresh)
            {
                const u64* hsrc = (const u64*)(hglob + ((size_t)(g * 2 + (t & 1))) * GB * HH);
                int b = tid >> 5, kc = tid & 31;
                #pragma unroll
                for (int i = 0; i < 2; ++i) {
                    int k = kc * 8 + i * 256;
                    u64 lo = __hip_atomic_load(hsrc + (b * HH + k) / 4,
                                               __ATOMIC_RELAXED, __HIP_MEMORY_SCOPE_AGENT);
                    u64 hi = __hip_atomic_load(hsrc + (b * HH + k) / 4 + 1,
                                               __ATOMIC_RELAXED, __HIP_MEMORY_SCOPE_AGENT);
                    int sk = k ^ ((b & 7) << 3);           // XOR moves 8-elem blocks whole
                    *(u64*)(&h_s[b * HH + sk])     = lo;
                    *(u64*)(&h_s[b * HH + sk + 4]) = hi;
                }
            }
            __syncthreads();                               // #4
        }
    }
}

extern "C" void kernel_launch(void* const* d_in, const int* in_sizes, int n_in,
                              void* d_out, int out_size, void* d_ws, size_t ws_size,
                              hipStream_t stream) {
    const float* inp = (const float*)d_in[0];
    const float* Wk  = (const float*)d_in[1];
    const float* Wr  = (const float*)d_in[2];
    const float* bg  = (const float*)d_in[3];
    const float* Wd  = (const float*)d_in[4];
    const float* bd  = (const float*)d_in[5];
    float* out = (float*)d_out;

    // ws layout: [0,16384): epoch flags, (g*32+s)*16 ints (64B apart)
    //            [16384, 16384+262144): h double buffers, 8 x 2 x 16 x 512 bf16
    char* ws = (char*)d_ws;
    int* bar = (int*)ws;
    u16* hglob = (u16*)(ws + 16384);
    size_t zbytes = 16384 + (size_t)NGRP * 2 * GB * HH * sizeof(u16);
    hipMemsetAsync(d_ws, 0, zbytes, stream);

    hipLaunchKernelGGL(mdn_kernel, dim3(NGRP * NSLICE), dim3(512), 0, stream,
                       inp, Wk, Wr, bg, Wd, bd, out, hglob, bar);
}